// Round 5
// baseline (254.706 us; speedup 1.0000x reference)
//
#include <hip/hip_runtime.h>
#include <math.h>

// LIF recurrence: v_t = v_{t-1}*decay*(1-z_{t-1}) + x_t ; z_t = (v_t > 0.3)
// x [B=128,T=2048,H=128] f32; out [B,T,H] f32 spikes.
//
// R5: wave-specialized pipeline with VGPR-load staging (no global_load_lds --
// R2-R4 evidence: LDS-DMA path caps at ~6 B/cyc/CU regardless of structure;
// VGPR loads scale with outstanding bytes, and per-wave vmcnt is private).
// 256 blocks x 512 threads (8 waves, 1 block/CU):
//   w0    : compute (64 serial chains, reads x-ring, writes z-ring)
//   w1..w6: loaders, tiles round-robin: global_load_dwordx4 x16 -> ds_write_b128
//   w7    : storer (z-ring -> regs -> flag slot free -> coalesced dwordx4 stores)
// Per-tile ready flags + consumed-counters in LDS. No __syncthreads in loop.

constexpr int Bdim = 128;
constexpr int Tdim = 2048;
constexpr int Hdim = 128;
constexpr int HW   = 64;          // chains per block
constexpr int Ut   = 64;          // timesteps per tile (16 KB)
constexpr int NT   = Tdim / Ut;   // 32 tiles
constexpr int NX   = 6;           // x-ring depth (96 KB)
constexpr int NZ   = 3;           // z-ring depth (48 KB)
constexpr int NLOAD = 6;          // loader waves
constexpr float VTH = 0.3f;

__device__ __forceinline__ void lgkm_fence() {
    asm volatile("s_waitcnt lgkmcnt(0)" ::: "memory");
}

__global__ __launch_bounds__(512) void lif_kernel(
    const float* __restrict__ x,
    const float* __restrict__ v0,
    const float* __restrict__ z0,
    const float* __restrict__ decay_raw,
    float* __restrict__ out)
{
    __shared__ float xbuf[NX][Ut][HW];
    __shared__ float zbuf[NZ][Ut][HW];
    __shared__ int   flags[NT + 8];   // [0..NT): xready ; NT: xc ; NT+1: zc ; NT+2: zs

    volatile int* vf = (volatile int*)flags;

    const int tid  = threadIdx.x;
    const int wave = tid >> 6;
    const int lane = tid & 63;
    const int blk  = blockIdx.x;
    const int b    = blk >> 1;
    const int h0   = (blk & 1) * HW;

    for (int i = tid; i < NT + 8; i += 512) flags[i] = 0;
    __syncthreads();                     // init only; nothing in flight yet

    const float* xbase = x   + (size_t)b * Tdim * Hdim + h0;
    float*       obase = out + (size_t)b * Tdim * Hdim + h0;
    // lane mapping (verified R2-R4): chunk j covers tile rows [4j,4j+4):
    // lane i -> row 4j+(i>>4), float col (i&15)*4.
    const int r_sub = lane >> 4;
    const int c_sub = (lane & 15) * 4;
    const int sub   = r_sub * Hdim + c_sub;

    if (wave >= 1 && wave <= NLOAD) {
        // ---------------- x loaders (VGPR -> LDS) ----------------
        for (int k = wave - 1; k < NT; k += NLOAD) {
            while (vf[NT] < k - NX + 1) __builtin_amdgcn_s_sleep(2);  // slot free
            const float* g = xbase + (size_t)k * Ut * Hdim + sub;
            float4 tmp[16];
            #pragma unroll
            for (int j = 0; j < 16; ++j)
                tmp[j] = *(const float4*)(g + (size_t)(4 * j) * Hdim);
            const int xb = k % NX;
            #pragma unroll
            for (int j = 0; j < 16; ++j)
                *(float4*)&xbuf[xb][4 * j + r_sub][c_sub] = tmp[j];
            lgkm_fence();                              // data visible in LDS
            if (lane == 0) vf[k] = 1;
        }
    } else if (wave == 0) {
        // ---------------- compute ----------------
        const float decay = 1.0f / (1.0f + expf(-decay_raw[h0 + lane]));
        float v = v0[b * Hdim + h0 + lane];
        float z = z0[b * Hdim + h0 + lane];

        for (int k = 0; k < NT; ++k) {
            while (vf[k] == 0)           __builtin_amdgcn_s_sleep(1); // x ready
            while (vf[NT + 2] < k - NZ + 1) __builtin_amdgcn_s_sleep(1); // z slot
            const int xb = k % NX, zb = k % NZ;
            #pragma unroll 16
            for (int t = 0; t < Ut; ++t) {
                const float xv = xbuf[xb][t][lane];
                const float s  = v * decay + xv;       // mul-then-add rounding
                v = (z > 0.5f) ? xv : s;               // z=1 -> exactly x
                z = (v > VTH) ? 1.0f : 0.0f;
                zbuf[zb][t][lane] = z;
            }
            lgkm_fence();                              // z visible
            if (lane == 0) { vf[NT + 1] = k + 1; vf[NT] = k + 1; }
        }
    } else {
        // ---------------- z storer ----------------
        for (int k = 0; k < NT; ++k) {
            while (vf[NT + 1] < k + 1) __builtin_amdgcn_s_sleep(1);
            const int zb = k % NZ;
            float4 vv[16];
            #pragma unroll
            for (int s = 0; s < 16; ++s)
                vv[s] = *(const float4*)&zbuf[zb][4 * s + r_sub][c_sub];
            lgkm_fence();                              // reads done -> slot free
            if (lane == 0) vf[NT + 2] = k + 1;
            float* op = obase + (size_t)k * Ut * Hdim + sub;
            #pragma unroll
            for (int s = 0; s < 16; ++s)
                *(float4*)(op + (size_t)(4 * s) * Hdim) = vv[s];
            // fire-and-forget; private vmcnt, no drain
        }
    }
}

extern "C" void kernel_launch(void* const* d_in, const int* in_sizes, int n_in,
                              void* d_out, int out_size, void* d_ws, size_t ws_size,
                              hipStream_t stream) {
    const float* x         = (const float*)d_in[0];
    const float* v0        = (const float*)d_in[1];
    const float* z0        = (const float*)d_in[2];
    const float* decay_raw = (const float*)d_in[3];
    float* out = (float*)d_out;

    lif_kernel<<<Bdim * Hdim / HW, 512, 0, stream>>>(x, v0, z0, decay_raw, out);
}

// Round 6
// 246.490 us; speedup vs baseline: 1.0333x; 1.0333x over previous
//
#include <hip/hip_runtime.h>
#include <math.h>

// LIF recurrence: v_t = v_{t-1}*decay*(1-z_{t-1}) + x_t ; z_t = (v_t > 0.3)
// x [B=128,T=2048,H=128] f32; out [B,T,H] f32 spikes.
//
// R6: two mono-traffic phases per block (R2-R5 showed mixed R/W from few waves
// caps at ~5 B/cyc/CU; write-only fillBuffer hits 10.7 B/cyc/CU).
//  Phase 1 (read-only): w0 computes the 64 serial chains and packs z as BITS
//    into a 16 KB LDS bitplane (2048 t x 64 h x 1 bit) -- no z global traffic.
//    w1..w7: x loaders (VGPR dwordx4 -> ds_write_b128), 8-tile ring (128 KB
//    address span for channel spread). Per-block start skew decorrelates the
//    t-lockstep address phase across blocks.
//  Phase 2 (write-only): one __syncthreads, then ALL 8 waves expand the LDS
//    bitplane to 512 KB of f32 spikes, pure streaming stores.

constexpr int Bdim = 128;
constexpr int Tdim = 2048;
constexpr int Hdim = 128;
constexpr int HW   = 64;          // chains per block
constexpr int Ut   = 64;          // timesteps per x tile (16 KB)
constexpr int NT   = Tdim / Ut;   // 32 tiles
constexpr int NX   = 8;           // x-ring depth (128 KB)
constexpr int NLOAD = 7;          // loader waves
constexpr float VTH = 0.3f;

__device__ __forceinline__ void lgkm_fence() {
    asm volatile("s_waitcnt lgkmcnt(0)" ::: "memory");
}

__global__ __launch_bounds__(512) void lif_kernel(
    const float* __restrict__ x,
    const float* __restrict__ v0,
    const float* __restrict__ z0,
    const float* __restrict__ decay_raw,
    float* __restrict__ out)
{
    __shared__ float    xbuf[NX][Ut][HW];            // 128 KB
    __shared__ unsigned zbits[Tdim / 32][HW];        // 16 KB: bit t&31 of word [t>>5][h]
    __shared__ int      flags[NT + 4];               // [0..NT): x ready ; [NT]: consumed

    volatile int* vf = (volatile int*)flags;

    const int tid  = threadIdx.x;
    const int wave = tid >> 6;
    const int lane = tid & 63;
    const int blk  = blockIdx.x;
    const int b    = blk >> 1;
    const int h0   = (blk & 1) * HW;

    for (int i = tid; i < NT + 4; i += 512) flags[i] = 0;
    __syncthreads();                                 // init only

    // small per-block start skew: decorrelate the time-lockstep address phase
    for (int i = 0; i < (blk & 3); ++i) __builtin_amdgcn_s_sleep(16);

    const float* xbase = x   + (size_t)b * Tdim * Hdim + h0;
    float*       obase = out + (size_t)b * Tdim * Hdim + h0;
    // lane mapping (verified R2-R5): chunk j covers tile rows [4j,4j+4):
    // lane i -> row 4j+(i>>4), float col (i&15)*4.
    const int r_sub = lane >> 4;
    const int c_sub = (lane & 15) * 4;
    const int sub   = r_sub * Hdim + c_sub;

    if (wave >= 1) {
        // ---------------- phase 1: x loaders ----------------
        for (int k = wave - 1; k < NT; k += NLOAD) {
            while (vf[NT] < k - (NX - 1)) __builtin_amdgcn_s_sleep(2);  // slot free
            const float* g = xbase + (size_t)k * Ut * Hdim + sub;
            float4 tmp[16];
            #pragma unroll
            for (int j = 0; j < 16; ++j)
                tmp[j] = *(const float4*)(g + (size_t)(4 * j) * Hdim);
            const int xb = k % NX;
            #pragma unroll
            for (int j = 0; j < 16; ++j)
                *(float4*)&xbuf[xb][4 * j + r_sub][c_sub] = tmp[j];
            lgkm_fence();                            // tile visible in LDS
            if (lane == 0) vf[k] = 1;
        }
    } else {
        // ---------------- phase 1: compute (chains + bit-pack) ----------------
        const float decay = 1.0f / (1.0f + expf(-decay_raw[h0 + lane]));
        float v = v0[b * Hdim + h0 + lane];
        float z = z0[b * Hdim + h0 + lane];

        for (int k = 0; k < NT; ++k) {
            while (vf[k] == 0) __builtin_amdgcn_s_sleep(1);            // x ready
            const int xb = k % NX;
            #pragma unroll
            for (int w32 = 0; w32 < Ut / 32; ++w32) {                  // 2 words/tile
                unsigned mask = 0u;
                #pragma unroll
                for (int tb = 0; tb < 32; ++tb) {
                    const int t = w32 * 32 + tb;
                    const float xv = xbuf[xb][t][lane];
                    const float s  = v * decay + xv;   // mul-then-add rounding
                    v = (z > 0.5f) ? xv : s;           // z=1 -> exactly x
                    const bool sp = (v > VTH);
                    z = sp ? 1.0f : 0.0f;
                    mask |= (sp ? 1u : 0u) << tb;
                }
                zbits[k * (Ut / 32) + w32][lane] = mask;
            }
            lgkm_fence();                             // tile reads done
            if (lane == 0) vf[NT] = k + 1;            // slot k free
        }
    }

    __syncthreads();                                  // zbits complete

    // ---------------- phase 2: write-only expand, all 8 waves ----------------
    // wave w covers t in [w*256, (w+1)*256): 256 rows x 256 B coalesced stores.
    {
        const int t0 = wave * (Tdim / 8);
        #pragma unroll 8
        for (int t = t0; t < t0 + Tdim / 8; ++t) {
            const unsigned word = zbits[t >> 5][lane];
            const float f = ((word >> (t & 31)) & 1u) ? 1.0f : 0.0f;
            obase[(size_t)t * Hdim + lane] = f;
        }
    }
}

extern "C" void kernel_launch(void* const* d_in, const int* in_sizes, int n_in,
                              void* d_out, int out_size, void* d_ws, size_t ws_size,
                              hipStream_t stream) {
    const float* x         = (const float*)d_in[0];
    const float* v0        = (const float*)d_in[1];
    const float* z0        = (const float*)d_in[2];
    const float* decay_raw = (const float*)d_in[3];
    float* out = (float*)d_out;

    lif_kernel<<<Bdim * Hdim / HW, 512, 0, stream>>>(x, v0, z0, decay_raw, out);
}